// Round 6
// baseline (143.012 us; speedup 1.0000x reference)
//
#include <hip/hip_runtime.h>
#include <math.h>

#define N_COLS 1024
#define NRINGS 8

// ---- geometry: 32 threads/row, 32 cols/thread, 2 rows per thread ----
#define TPR    32
#define CHUNK  32
#define PAIRS_PER_BLOCK 8         // 256 threads / 32 lanes-per-pair -> 16 rows/block

// Single fused kernel. R5 post-mortem: a second kernel node costs ~16us of
// wall (R1 1-kernel overhead 63us vs R2/R4/R5 2-kernel ~80us), and the
// global->ws->LDS table round-trip adds drain coupling. Fix: build each
// ring's (c,s)/F/A tables IN-BLOCK, per-ring, double-buffered in LDS.
// Build cost: 4 sincos/thread/ring (~60 VALU) vs ~600 VALU of ring compute.
// Angles for ring r+1 are prefetched (coalesced float4, L3-hot) before
// compute of ring r; compiler-scheduled early, waitcnt lands in build.
//
// Table layout per buffer nb:
//   sCS[nb][jp*32 + t] : float4 (c_j0,s_j0,c_j1,s_j1), j = 2jp, k = t*32+j
//   sF [nb][q*32  + t] : float4 f_{4q..4q+3}, f_j = c_j * prod_{l>j in chunk}(-s_l)
//   sA [nb][t]         : prod_j(-s_j) over chunk t
//   sAux[nb]           : real (c,s) at k=1023 (table entry doctored to
//                        (0,-1) = exact no-op chain step)
__global__ __launch_bounds__(256, 2)
void ced_fused(const float* __restrict__ x,
               const float* __restrict__ ae,
               const float* __restrict__ ad,
               const float* __restrict__ hw,
               const float* __restrict__ hs,
               float* __restrict__ out, int B)
{
    __shared__ float4 sCS[2][512];    // 16 KB
    __shared__ float4 sF [2][256];    //  8 KB
    __shared__ float  sA [2][32];
    __shared__ float2 sAux[2];

    const int tid  = threadIdx.x;
    const int lane = tid & 63;
    const int t    = lane & 31;           // chunk index within row (compute)
    const int groupBase = lane & 32;
    const int pairRow = blockIdx.x * PAIRS_PER_BLOCK + (tid >> 5);
    const size_t rowA = (size_t)(2 * pairRow) * N_COLS;
    const size_t rowB = rowA + N_COLS;

    // build-phase mapping: thread owns angles k = 4*tid .. 4*tid+3
    const int bt = tid >> 3;              // chunk 0..31
    const int bq = tid & 7;               // 4-angle segment 0..7 within chunk

    // ---- load x (2 rows) ----
    float ya[CHUNK], yb[CHUNK];
    {
        const float4* xa = (const float4*)(x + rowA + t * CHUNK);
        const float4* xb = (const float4*)(x + rowB + t * CHUNK);
        #pragma unroll
        for (int i = 0; i < 8; ++i) {
            float4 va = xa[i], vb = xb[i];
            ya[4*i] = va.x; ya[4*i+1] = va.y; ya[4*i+2] = va.z; ya[4*i+3] = va.w;
            yb[4*i] = vb.x; yb[4*i+1] = vb.y; yb[4*i+2] = vb.z; yb[4*i+3] = vb.w;
        }
    }

    const float w   = 1.f / (1.f + expf(-hw[0]));
    const float omw = 1.f - w;

    // ================= in-block table build for one ring =================
    auto build = [&](float4 av, int nb) {
        float c0, s0, c1, s1, c2, s2, c3, s3;
        sincosf(av.x, &s0, &c0);
        sincosf(av.y, &s1, &c1);
        sincosf(av.z, &s2, &c2);
        sincosf(av.w, &s3, &c3);
        if (tid == 255) {                 // k = 1023: doctored no-op step
            sAux[nb] = make_float2(c3, s3);
            c3 = 0.f; s3 = -1.f;
        }
        sCS[nb][(2*bq    )*32 + bt] = make_float4(c0, s0, c1, s1);
        sCS[nb][(2*bq + 1)*32 + bt] = make_float4(c2, s2, c3, s3);

        // local suffix products within the 4-segment
        float f3 = c3;       float P = -s3;
        float f2 = c2 * P;   P *= -s2;
        float f1 = c1 * P;   P *= -s1;
        float f0 = c0 * P;   P *= -s0;    // P = prod over segment

        float ip = P;                     // inclusive suffix over segments q..7
        #pragma unroll
        for (int d = 1; d < 8; d <<= 1) {
            float tmp = __shfl_down(ip, d);
            if (bq + d < 8) ip *= tmp;
        }
        float ex = __shfl_down(ip, 1);    // exclusive suffix
        if (bq == 7) ex = 1.f;
        sF[nb][bq*32 + bt] = make_float4(f0*ex, f1*ex, f2*ex, f3*ex);
        if (bq == 0) sA[nb][bt] = ip;
    };

    // ---- build ring 0 into buffer 0 ----
    build(*(const float4*)(ae + tid * 4), 0);
    __syncthreads();

    #pragma unroll 1
    for (int r = 0; r < NRINGS; ++r) {
        const int buf = r & 1;

        // prefetch next ring's angles (consumed in build after compute)
        float4 av;
        if (r < NRINGS - 1) {
            const int rr = r + 1;
            const float* base = (rr < 4) ? (ae + (rr << 10)) : (ad + ((rr - 4) << 10));
            av = *(const float4*)(base + tid * 4);
        }

        if (r == 4) {                     // bottleneck blend + output 0
            float4* oa = (float4*)(out + rowA + t * CHUNK);
            float4* ob = (float4*)(out + rowB + t * CHUNK);
            const float4* hp = (const float4*)(hs + t * CHUNK);
            #pragma unroll
            for (int i = 0; i < 8; ++i) {
                float4 h = hp[i];
                float4 na, nb2;
                na.x  = fmaf(omw, ya[4*i+0], w * h.x);
                na.y  = fmaf(omw, ya[4*i+1], w * h.y);
                na.z  = fmaf(omw, ya[4*i+2], w * h.z);
                na.w  = fmaf(omw, ya[4*i+3], w * h.w);
                nb2.x = fmaf(omw, yb[4*i+0], w * h.x);
                nb2.y = fmaf(omw, yb[4*i+1], w * h.y);
                nb2.z = fmaf(omw, yb[4*i+2], w * h.z);
                nb2.w = fmaf(omw, yb[4*i+3], w * h.w);
                oa[i] = na; ob[i] = nb2;
                ya[4*i+0] = na.x;  ya[4*i+1] = na.y;  ya[4*i+2] = na.z;  ya[4*i+3] = na.w;
                yb[4*i+0] = nb2.x; yb[4*i+1] = nb2.y; yb[4*i+2] = nb2.z; yb[4*i+3] = nb2.w;
            }
        }

        const float4* csL = sCS[buf];     // + jp*32 + t
        const float4* fL  = sF [buf];     // + qi*32 + t
        const float2  cN  = sAux[buf];
        const float   saI = sA[buf][t];

        float y0a = __shfl(ya[0],       groupBase);
        float yNa = __shfl(ya[CHUNK-1], groupBase + 31);
        float y0b = __shfl(yb[0],       groupBase);
        float yNb = __shfl(yb[CHUNK-1], groupBase + 31);
        float CinitA = cN.x * yNa - cN.y * y0a;
        float CinitB = cN.x * yNb - cN.y * y0b;
        float x0nA   = fmaf(cN.y, yNa, cN.x * y0a);
        float x0nB   = fmaf(cN.y, yNb, cN.x * y0b);
        if (t == 0) { ya[0] = x0nA; yb[0] = x0nB; }

        // ---- pass 1: two independent local chains (carry_in = 0) ----
        float carA = 0.f, carB = 0.f, ztA = 0.f, ztB = 0.f;
        #pragma unroll
        for (int jp = CHUNK/2 - 1; jp >= 0; --jp) {
            float4 cs4 = csL[jp * 32 + t];        // (c_j0,s_j0,c_j1,s_j1)
            const int j1 = 2*jp + 1;
            float z1a = fmaf(cs4.w, ya[j1], cs4.z * carA);
            float z1b = fmaf(cs4.w, yb[j1], cs4.z * carB);
            carA = fmaf(-cs4.w, carA, cs4.z * ya[j1]);
            carB = fmaf(-cs4.w, carB, cs4.z * yb[j1]);
            if (j1 == CHUNK - 1) { ztA = z1a; ztB = z1b; }
            else                 { ya[j1+1] = z1a; yb[j1+1] = z1b; }
            const int j0 = 2*jp;
            float z0a = fmaf(cs4.y, ya[j0], cs4.x * carA);
            float z0b = fmaf(cs4.y, yb[j0], cs4.x * carB);
            carA = fmaf(-cs4.y, carA, cs4.x * ya[j0]);
            carB = fmaf(-cs4.y, carB, cs4.x * yb[j0]);
            ya[j0+1] = z0a; yb[j0+1] = z0b;
        }

        // ---- affine suffix scan over 32 lanes (sa shared across rows) ----
        float sa = saI;
        float sbA = carA, sbB = carB;
        #pragma unroll
        for (int d = 1; d < TPR; d <<= 1) {
            float a2  = __shfl_down(sa,  d);
            float b2a = __shfl_down(sbA, d);
            float b2b = __shfl_down(sbB, d);
            if (t + d < TPR) {
                sbA = fmaf(sa, b2a, sbA);
                sbB = fmaf(sa, b2b, sbB);
                sa *= a2;
            }
        }
        float ea  = __shfl_down(sa,  1);
        float ebA = __shfl_down(sbA, 1);
        float ebB = __shfl_down(sbB, 1);
        float zfA = fmaf(sa, CinitA, sbA);        // lane0: final z[0]
        float zfB = fmaf(sa, CinitB, sbB);
        float CinA = (t == TPR - 1) ? CinitA : fmaf(ea, CinitA, ebA);
        float CinB = (t == TPR - 1) ? CinitB : fmaf(ea, CinitB, ebB);

        // ---- pass 2: independent fix-up with precomputed f ----
        #pragma unroll
        for (int qi = CHUNK/4 - 1; qi >= 0; --qi) {
            float4 f4 = fL[qi * 32 + t];
            const int j = 4*qi;
            if (j + 3 == CHUNK - 1) { ztA = fmaf(f4.w, CinA, ztA);
                                      ztB = fmaf(f4.w, CinB, ztB); }
            else                    { ya[j+4] = fmaf(f4.w, CinA, ya[j+4]);
                                      yb[j+4] = fmaf(f4.w, CinB, yb[j+4]); }
            ya[j+3] = fmaf(f4.z, CinA, ya[j+3]);  yb[j+3] = fmaf(f4.z, CinB, yb[j+3]);
            ya[j+2] = fmaf(f4.y, CinA, ya[j+2]);  yb[j+2] = fmaf(f4.y, CinB, yb[j+2]);
            ya[j+1] = fmaf(f4.x, CinA, ya[j+1]);  yb[j+1] = fmaf(f4.x, CinB, yb[j+1]);
        }

        float upA = __shfl_up(ztA, 1);            // lane t-1's top -> slot 32t
        float upB = __shfl_up(ztB, 1);
        ya[0] = (t == 0) ? zfA : upA;
        yb[0] = (t == 0) ? zfB : upB;

        // ---- build ring r+1 into the other buffer ----
        // safe: ring r reads buf, build writes buf^1; waves still computing
        // ring r can't be hurt (disjoint buffers); barrier below publishes.
        if (r < NRINGS - 1) {
            build(av, buf ^ 1);
            __syncthreads();
        }
    }

    float4* oa = (float4*)(out + (size_t)B * N_COLS + rowA + t * CHUNK);
    float4* ob = (float4*)(out + (size_t)B * N_COLS + rowB + t * CHUNK);
    #pragma unroll
    for (int i = 0; i < 8; ++i) {
        oa[i] = make_float4(ya[4*i], ya[4*i+1], ya[4*i+2], ya[4*i+3]);
        ob[i] = make_float4(yb[4*i], yb[4*i+1], yb[4*i+2], yb[4*i+3]);
    }
}

// ============================  launcher  ================================
extern "C" void kernel_launch(void* const* d_in, const int* in_sizes, int n_in,
                              void* d_out, int out_size, void* d_ws, size_t ws_size,
                              hipStream_t stream) {
    const float* x  = (const float*)d_in[0];
    const float* ae = (const float*)d_in[1];
    const float* ad = (const float*)d_in[2];
    const float* hw = (const float*)d_in[3];
    const float* hs = (const float*)d_in[4];
    float* out = (float*)d_out;
    const int B = in_sizes[0] / N_COLS;          // 8192

    hipLaunchKernelGGL(ced_fused, dim3(B / (2 * PAIRS_PER_BLOCK)), dim3(256),
                       0, stream, x, ae, ad, hw, hs, out, B);
}